// Round 1
// baseline (3901.689 us; speedup 1.0000x reference)
//
#include <hip/hip_runtime.h>
#include <cstdint>
#include <cstddef>

// Problem constants: B=64, T=512, D=256, H=512
#define T_STEPS 512
#define D_DIM 256
#define H_DIM 512
#define B_SZ 64

// Scan decomposition: 4 column-groups of 128 cols per batch row.
// grid = 64 rows x 4 cg = 256 WGs of 512 threads; Wh slice (512x128 fp32)
// register-resident (128 VGPR/thread). Quartet members are blockIdx stride-64
// apart -> same XCD under the measured %8 mapping (perf heuristic only).
//
// Exchange (new): per-kc PARTIAL packets published straight out of the GEMM
// (no barrier / LDS combine hop). Dual path:
//   zfast: plain write-back stores + sc0 (L1-bypass, L2-hit) polls  -- fast
//   zslow: agent-scope mirror (always written)                      -- correct
// Consumers try fast with an iteration cap; on miss they go sticky-slow.
// Correctness never depends on WG->XCD placement.
#define NCG 4
#define CGW (H_DIM / NCG)   // 128
#define NTH 512
#define POLL_CAP 4096

// d_ws layout (>=4MB path): zfast u64[64][2][4][512] (2MB), zslow same (2MB).
// Poison never matches tags 1..512 (ws re-poisoned per bench iteration).

// ---------------------------------------------------------------------------
// Kernel 1: xproj = inputs @ Wx + bias  ->  d_out  [B*T, H]   (unchanged)
// ---------------------------------------------------------------------------
#define BM 64
#define BN 128
#define BK 32

__global__ __launch_bounds__(256)
void xproj_gemm(const float* __restrict__ A, const float* __restrict__ Bm,
                const float* __restrict__ bias, float* __restrict__ C,
                int M, int N, int K) {
    __shared__ float As[BK][BM];
    __shared__ float Bs[BK][BN];

    const int tid = threadIdx.x;
    const int tx = tid & 15;
    const int ty = tid >> 4;
    const int row0 = blockIdx.y * BM;
    const int col0 = blockIdx.x * BN;

    float acc[4][8];
    #pragma unroll
    for (int i = 0; i < 4; ++i)
        #pragma unroll
        for (int j = 0; j < 8; ++j) acc[i][j] = 0.0f;

    for (int kt = 0; kt < K; kt += BK) {
        #pragma unroll
        for (int i = 0; i < 2; ++i) {
            int q  = tid + i * 256;
            int m  = q >> 3;
            int k4 = (q & 7) << 2;
            float4 v = *(const float4*)&A[(size_t)(row0 + m) * K + kt + k4];
            As[k4 + 0][m] = v.x; As[k4 + 1][m] = v.y;
            As[k4 + 2][m] = v.z; As[k4 + 3][m] = v.w;
        }
        #pragma unroll
        for (int i = 0; i < 4; ++i) {
            int q  = tid + i * 256;
            int kk = q >> 5;
            int n4 = (q & 31) << 2;
            *(float4*)&Bs[kk][n4] = *(const float4*)&Bm[(size_t)(kt + kk) * N + col0 + n4];
        }
        __syncthreads();
        #pragma unroll
        for (int k = 0; k < BK; ++k) {
            float4 a  = *(const float4*)&As[k][ty << 2];
            float4 b0 = *(const float4*)&Bs[k][tx << 2];
            float4 b1 = *(const float4*)&Bs[k][(tx << 2) + 64];
            float av[4] = {a.x, a.y, a.z, a.w};
            float bv[8] = {b0.x, b0.y, b0.z, b0.w, b1.x, b1.y, b1.z, b1.w};
            #pragma unroll
            for (int i = 0; i < 4; ++i)
                #pragma unroll
                for (int j = 0; j < 8; ++j)
                    acc[i][j] = fmaf(av[i], bv[j], acc[i][j]);
        }
        __syncthreads();
    }

    float bv0[4], bv1[4];
    #pragma unroll
    for (int j = 0; j < 4; ++j) {
        bv0[j] = bias[col0 + (tx << 2) + j];
        bv1[j] = bias[col0 + (tx << 2) + 64 + j];
    }
    #pragma unroll
    for (int i = 0; i < 4; ++i) {
        int r = row0 + (ty << 2) + i;
        float4 o0 = make_float4(acc[i][0] + bv0[0], acc[i][1] + bv0[1],
                                acc[i][2] + bv0[2], acc[i][3] + bv0[3]);
        float4 o1 = make_float4(acc[i][4] + bv1[0], acc[i][5] + bv1[1],
                                acc[i][6] + bv1[2], acc[i][7] + bv1[3]);
        *(float4*)&C[(size_t)r * N + col0 + (tx << 2)]      = o0;
        *(float4*)&C[(size_t)r * N + col0 + (tx << 2) + 64] = o1;
    }
}

// ---------------------------------------------------------------------------
__device__ __forceinline__ float tanh_fast(float x) {
    float ax = fabsf(x);
    float e  = __expf(2.0f * ax);
    float t  = 1.0f - 2.0f / (e + 1.0f);
    return copysignf(t, x);
}

// ---------------------------------------------------------------------------
// Kernel 2 (new): partial-publish + dual-path exchange.
// Per step per thread: 128-FMA partial (4 chains) -> publish (plain + agent
// mirror) -> gather 4 partials for own global column -> LN -> tanh -> store.
// h_s double-buffered: 2 barriers/step (B: LN cross-wave, C: h publish).
// ---------------------------------------------------------------------------
__global__ __launch_bounds__(NTH)
void rnn_scan4(const float* __restrict__ Wh, const float* __restrict__ h0,
               const float* __restrict__ gamma, const float* __restrict__ beta,
               float* __restrict__ out,
               unsigned long long* __restrict__ zfast,
               unsigned long long* __restrict__ zslow) {
    const int r   = blockIdx.x & (B_SZ - 1);   // row; quartet shares r
    const int cg  = blockIdx.x >> 6;           // 0..3 (stride 64 -> same XCD)
    const int tid = threadIdx.x;               // 0..511
    const int c   = tid & (CGW - 1);           // 0..127
    const int kc  = tid >> 7;                  // 0..3 (wave-uniform)

    __shared__ float h_s[2][H_DIM];
    __shared__ float wred_s[16];

    // Wh register slice: w[j] = Wh[kc*128 + j][cg*128 + c]
    float w[128];
    #pragma unroll
    for (int j = 0; j < 128; ++j)
        w[j] = Wh[(size_t)(kc * 128 + j) * H_DIM + cg * CGW + c];

    h_s[0][tid] = h0[r * H_DIM + tid];
    const float g_own = gamma[tid];
    const float b_own = beta[tid];
    float* outrow = out + (size_t)r * T_STEPS * H_DIM;

    unsigned long long* zf0 = zfast + (size_t)r * 2 * (NCG * H_DIM);
    unsigned long long* zs0 = zslow + (size_t)r * 2 * (NCG * H_DIM);
    const int pub_off = kc * H_DIM + cg * CGW + c;   // within one parity block

    // xp prefetch one step ahead; xp is folded into the kc==0 partial, so only
    // tid<CGW (== kc==0, wave-aligned) loads it. NT: streamed, read-once.
    float xp_next = 0.0f;
    if (tid < CGW)
        xp_next = __builtin_nontemporal_load(&outrow[cg * CGW + tid]);
    int fastmode = 1;
    __syncthreads();

    for (int t = 0; t < T_STEPS; ++t) {
        unsigned long long* zf = zf0 + (size_t)(t & 1) * (NCG * H_DIM);
        unsigned long long* zs = zs0 + (size_t)(t & 1) * (NCG * H_DIM);
        const unsigned int tag = (unsigned int)(t + 1);
        const float xp = xp_next;              // valid for tid<CGW

        // partial z for own (column, k-chunk): 4 independent FMA chains
        const float4* h4 = (const float4*)&h_s[t & 1][kc * 128];
        float a0 = 0.0f, a1 = 0.0f, a2 = 0.0f, a3 = 0.0f;
        #pragma unroll
        for (int j4 = 0; j4 < 32; ++j4) {
            float4 hv = h4[j4];
            a0 = fmaf(w[4 * j4 + 0], hv.x, a0);
            a1 = fmaf(w[4 * j4 + 1], hv.y, a1);
            a2 = fmaf(w[4 * j4 + 2], hv.z, a2);
            a3 = fmaf(w[4 * j4 + 3], hv.w, a3);
        }
        float part = (a0 + a1) + (a2 + a3);
        if (tid < CGW) part = xp + part;       // fold xp into kc==0 partial

        // publish: plain write-back store (fast, L2) + agent mirror (correct)
        const unsigned long long pkt =
            ((unsigned long long)tag << 32) | (unsigned long long)__float_as_uint(part);
        asm volatile("global_store_dwordx2 %0, %1, off"
                     :: "v"(&zf[pub_off]), "v"(pkt) : "memory");
        __hip_atomic_store(&zs[pub_off], pkt,
                           __ATOMIC_RELAXED, __HIP_MEMORY_SCOPE_AGENT);

        // prefetch next xp while the publish drains
        if (tid < CGW && t + 1 < T_STEPS)
            xp_next = __builtin_nontemporal_load(
                &outrow[(size_t)(t + 1) * H_DIM + cg * CGW + tid]);

        // ---- gather the 4 partials for own global column `tid` ----
        unsigned long long p0, p1, p2, p3;
        bool ok = false;
        if (fastmode) {
            const unsigned long long* f0 = &zf[0 * H_DIM + tid];
            const unsigned long long* f1 = &zf[1 * H_DIM + tid];
            const unsigned long long* f2 = &zf[2 * H_DIM + tid];
            const unsigned long long* f3 = &zf[3 * H_DIM + tid];
            #pragma unroll 1
            for (int it = 0; it < POLL_CAP; ++it) {
                asm volatile(
                    "global_load_dwordx2 %0, %4, off sc0\n\t"
                    "global_load_dwordx2 %1, %5, off sc0\n\t"
                    "global_load_dwordx2 %2, %6, off sc0\n\t"
                    "global_load_dwordx2 %3, %7, off sc0\n\t"
                    "s_waitcnt vmcnt(0)"
                    : "=&v"(p0), "=&v"(p1), "=&v"(p2), "=&v"(p3)
                    : "v"(f0), "v"(f1), "v"(f2), "v"(f3)
                    : "memory");
                if ((unsigned)(p0 >> 32) == tag && (unsigned)(p1 >> 32) == tag &&
                    (unsigned)(p2 >> 32) == tag && (unsigned)(p3 >> 32) == tag) {
                    ok = true; break;
                }
            }
            if (!ok) fastmode = 0;             // sticky fallback
        }
        if (!ok) {
            bool g0 = false, g1 = false, g2 = false, g3 = false;
            do {
                if (!g0) { unsigned long long v = __hip_atomic_load(&zs[0 * H_DIM + tid], __ATOMIC_RELAXED, __HIP_MEMORY_SCOPE_AGENT); if ((unsigned)(v >> 32) == tag) { p0 = v; g0 = true; } }
                if (!g1) { unsigned long long v = __hip_atomic_load(&zs[1 * H_DIM + tid], __ATOMIC_RELAXED, __HIP_MEMORY_SCOPE_AGENT); if ((unsigned)(v >> 32) == tag) { p1 = v; g1 = true; } }
                if (!g2) { unsigned long long v = __hip_atomic_load(&zs[2 * H_DIM + tid], __ATOMIC_RELAXED, __HIP_MEMORY_SCOPE_AGENT); if ((unsigned)(v >> 32) == tag) { p2 = v; g2 = true; } }
                if (!g3) { unsigned long long v = __hip_atomic_load(&zs[3 * H_DIM + tid], __ATOMIC_RELAXED, __HIP_MEMORY_SCOPE_AGENT); if ((unsigned)(v >> 32) == tag) { p3 = v; g3 = true; } }
            } while (!(g0 && g1 && g2 && g3));
        }

        // z fold order matches the old kernel: ((((xp)+p0)+p1)+p2)+p3
        float z = __uint_as_float((unsigned)p0);
        z += __uint_as_float((unsigned)p1);
        z += __uint_as_float((unsigned)p2);
        z += __uint_as_float((unsigned)p3);

        // LN stats over 512: wave shuffle + LDS, combined redundantly by all
        float s = z, q = z * z;
        #pragma unroll
        for (int o = 32; o > 0; o >>= 1) {
            s += __shfl_down(s, o, 64);
            q += __shfl_down(q, o, 64);
        }
        const int wid = tid >> 6;
        if ((tid & 63) == 0) { wred_s[wid] = s; wred_s[8 + wid] = q; }
        __syncthreads();                                   // barrier B
        float S = 0.0f, Q = 0.0f;
        #pragma unroll
        for (int i = 0; i < 8; ++i) { S += wred_s[i]; Q += wred_s[8 + i]; }
        float mean = S * (1.0f / H_DIM);
        float var  = Q * (1.0f / H_DIM) - mean * mean;
        float rstd = rsqrtf(var + 1e-3f);                  // keras LN eps

        float hn = tanh_fast((z - mean) * rstd * g_own + b_own);
        if (kc == cg)
            __builtin_nontemporal_store(hn, &outrow[(size_t)t * H_DIM + tid]);
        h_s[(t & 1) ^ 1][tid] = hn;            // double buffer: no read hazard
        __syncthreads();                                   // barrier C
    }
}

// ---------------------------------------------------------------------------
// Fallback (ws < 4MB): the previous harness-verified kernel, verbatim.
// ---------------------------------------------------------------------------
__global__ __launch_bounds__(NTH)
void rnn_scan3(const float* __restrict__ Wh, const float* __restrict__ h0,
               const float* __restrict__ gamma, const float* __restrict__ beta,
               float* __restrict__ out,
               unsigned long long* __restrict__ zbuf) {
    const int r   = blockIdx.x & (B_SZ - 1);
    const int cg  = blockIdx.x >> 6;
    const int tid = threadIdx.x;
    const int c   = tid & (CGW - 1);
    const int kc  = tid >> 7;

    __shared__ float h_s[H_DIM];
    __shared__ float part_s[NCG][CGW];
    __shared__ float wred_s[16];

    float w[128];
    #pragma unroll
    for (int j = 0; j < 128; ++j)
        w[j] = Wh[(size_t)(kc * 128 + j) * H_DIM + cg * CGW + c];

    h_s[tid] = h0[r * H_DIM + tid];
    const float g_own = gamma[tid];
    const float b_own = beta[tid];
    float* outrow = out + (size_t)r * T_STEPS * H_DIM;
    unsigned long long* zrow0 = zbuf + (size_t)(r * 2) * H_DIM;
    __syncthreads();

    for (int t = 0; t < T_STEPS; ++t) {
        unsigned long long* zrow = zrow0 + (size_t)(t & 1) * H_DIM;
        const unsigned int tag = (unsigned int)(t + 1);

        float xp = 0.0f;
        if (tid < CGW) xp = outrow[t * H_DIM + cg * CGW + tid];

        float acc = 0.0f;
        const float4* h4 = (const float4*)&h_s[kc * 128];
        #pragma unroll
        for (int j4 = 0; j4 < 32; ++j4) {
            float4 hv = h4[j4];
            acc = fmaf(w[4 * j4 + 0], hv.x, acc);
            acc = fmaf(w[4 * j4 + 1], hv.y, acc);
            acc = fmaf(w[4 * j4 + 2], hv.z, acc);
            acc = fmaf(w[4 * j4 + 3], hv.w, acc);
        }
        part_s[kc][c] = acc;
        __syncthreads();

        if (tid < CGW) {
            float z = xp + part_s[0][tid] + part_s[1][tid]
                         + part_s[2][tid] + part_s[3][tid];
            unsigned long long pkt =
                ((unsigned long long)tag << 32) | (unsigned long long)__float_as_uint(z);
            __hip_atomic_store(&zrow[cg * CGW + tid], pkt,
                               __ATOMIC_RELAXED, __HIP_MEMORY_SCOPE_AGENT);
        }

        unsigned long long pkt;
        do {
            pkt = __hip_atomic_load(&zrow[tid], __ATOMIC_RELAXED,
                                    __HIP_MEMORY_SCOPE_AGENT);
        } while ((unsigned int)(pkt >> 32) != tag);
        float z = __uint_as_float((unsigned int)pkt);

        float s = z, q = z * z;
        #pragma unroll
        for (int o = 32; o > 0; o >>= 1) {
            s += __shfl_down(s, o, 64);
            q += __shfl_down(q, o, 64);
        }
        const int wid = tid >> 6;
        if ((tid & 63) == 0) { wred_s[wid] = s; wred_s[8 + wid] = q; }
        __syncthreads();
        float S = 0.0f, Q = 0.0f;
        #pragma unroll
        for (int i = 0; i < 8; ++i) { S += wred_s[i]; Q += wred_s[8 + i]; }
        float mean = S * (1.0f / H_DIM);
        float var  = Q * (1.0f / H_DIM) - mean * mean;
        float rstd = rsqrtf(var + 1e-3f);

        float hn = tanh_fast((z - mean) * rstd * g_own + b_own);
        if (kc == cg) outrow[t * H_DIM + tid] = hn;
        h_s[tid] = hn;
        __syncthreads();
    }
}

// ---------------------------------------------------------------------------
extern "C" void kernel_launch(void* const* d_in, const int* in_sizes, int n_in,
                              void* d_out, int out_size, void* d_ws, size_t ws_size,
                              hipStream_t stream) {
    const float* inputs = (const float*)d_in[0];  // [B,T,D]
    const float* h0     = (const float*)d_in[1];  // [B,H]
    const float* Wx     = (const float*)d_in[2];  // [D,H]
    const float* Wh     = (const float*)d_in[3];  // [H,H]
    const float* bias   = (const float*)d_in[4];  // [H]
    const float* gamma  = (const float*)d_in[5];  // [H]
    const float* beta   = (const float*)d_in[6];  // [H]
    float* out = (float*)d_out;                   // [B,T,H]

    const int M = B_SZ * T_STEPS;                 // 32768
    dim3 g1(H_DIM / BN, M / BM);                  // (4, 512)
    xproj_gemm<<<g1, 256, 0, stream>>>(inputs, Wx, bias, out, M, H_DIM, D_DIM);

    if (ws_size >= (size_t)(4u << 20)) {
        unsigned long long* zfast = (unsigned long long*)d_ws;                  // 2 MB
        unsigned long long* zslow = zfast + (size_t)B_SZ * 2 * NCG * H_DIM;     // 2 MB
        rnn_scan4<<<B_SZ * NCG, NTH, 0, stream>>>(Wh, h0, gamma, beta, out,
                                                  zfast, zslow);
    } else {
        rnn_scan3<<<B_SZ * NCG, NTH, 0, stream>>>(Wh, h0, gamma, beta, out,
                                                  (unsigned long long*)d_ws);
    }
}

// Round 2
// 3170.674 us; speedup vs baseline: 1.2306x; 1.2306x over previous
//
#include <hip/hip_runtime.h>
#include <cstdint>
#include <cstddef>

// Problem constants: B=64, T=512, D=256, H=512
#define T_STEPS 512
#define D_DIM 256
#define H_DIM 512
#define B_SZ 64

// Scan decomposition (rnn_scan5): 4 rows per WG x 4 column-groups.
// grid = 16 rowgroups x 4 cg = 64 WGs of 512 threads, all co-resident
// (correctness requires only that the 4 WGs sharing a rowgroup are resident).
// Wh slice (512x128 fp32 = 128 VGPR/thread) is register-resident and SHARED
// across the 4 rows -- the whole point: 4 independent recurrences interleave
// so the agent-scope exchange latency of one row hides under the FMA/LN work
// of the others. Exchange protocol = proven scan3: combined (tag|z) u64
// packet, relaxed AGENT scope, one poll per (row, column).
#define NCG 4
#define CGW (H_DIM / NCG)   // 128
#define NTH 512
#define RPW 4               // rows per WG; code assumes RPW == NCG == 4
#define RGN (B_SZ / RPW)    // 16 rowgroups

// d_ws layout: zbuf u64[64 rows][2 parity][512 cols] = 512 KB.
// 0xAAAAAAAA poison never equals a tag in 1..512; ws re-poisoned per iter.

// ---------------------------------------------------------------------------
// Kernel 1: xproj = inputs @ Wx + bias  ->  d_out  [B*T, H]   (unchanged)
// ---------------------------------------------------------------------------
#define BM 64
#define BN 128
#define BK 32

__global__ __launch_bounds__(256)
void xproj_gemm(const float* __restrict__ A, const float* __restrict__ Bm,
                const float* __restrict__ bias, float* __restrict__ C,
                int M, int N, int K) {
    __shared__ float As[BK][BM];
    __shared__ float Bs[BK][BN];

    const int tid = threadIdx.x;
    const int tx = tid & 15;
    const int ty = tid >> 4;
    const int row0 = blockIdx.y * BM;
    const int col0 = blockIdx.x * BN;

    float acc[4][8];
    #pragma unroll
    for (int i = 0; i < 4; ++i)
        #pragma unroll
        for (int j = 0; j < 8; ++j) acc[i][j] = 0.0f;

    for (int kt = 0; kt < K; kt += BK) {
        #pragma unroll
        for (int i = 0; i < 2; ++i) {
            int q  = tid + i * 256;
            int m  = q >> 3;
            int k4 = (q & 7) << 2;
            float4 v = *(const float4*)&A[(size_t)(row0 + m) * K + kt + k4];
            As[k4 + 0][m] = v.x; As[k4 + 1][m] = v.y;
            As[k4 + 2][m] = v.z; As[k4 + 3][m] = v.w;
        }
        #pragma unroll
        for (int i = 0; i < 4; ++i) {
            int q  = tid + i * 256;
            int kk = q >> 5;
            int n4 = (q & 31) << 2;
            *(float4*)&Bs[kk][n4] = *(const float4*)&Bm[(size_t)(kt + kk) * N + col0 + n4];
        }
        __syncthreads();
        #pragma unroll
        for (int k = 0; k < BK; ++k) {
            float4 a  = *(const float4*)&As[k][ty << 2];
            float4 b0 = *(const float4*)&Bs[k][tx << 2];
            float4 b1 = *(const float4*)&Bs[k][(tx << 2) + 64];
            float av[4] = {a.x, a.y, a.z, a.w};
            float bv[8] = {b0.x, b0.y, b0.z, b0.w, b1.x, b1.y, b1.z, b1.w};
            #pragma unroll
            for (int i = 0; i < 4; ++i)
                #pragma unroll
                for (int j = 0; j < 8; ++j)
                    acc[i][j] = fmaf(av[i], bv[j], acc[i][j]);
        }
        __syncthreads();
    }

    float bv0[4], bv1[4];
    #pragma unroll
    for (int j = 0; j < 4; ++j) {
        bv0[j] = bias[col0 + (tx << 2) + j];
        bv1[j] = bias[col0 + (tx << 2) + 64 + j];
    }
    #pragma unroll
    for (int i = 0; i < 4; ++i) {
        int r = row0 + (ty << 2) + i;
        float4 o0 = make_float4(acc[i][0] + bv0[0], acc[i][1] + bv0[1],
                                acc[i][2] + bv0[2], acc[i][3] + bv0[3]);
        float4 o1 = make_float4(acc[i][4] + bv1[0], acc[i][5] + bv1[1],
                                acc[i][6] + bv1[2], acc[i][7] + bv1[3]);
        *(float4*)&C[(size_t)r * N + col0 + (tx << 2)]      = o0;
        *(float4*)&C[(size_t)r * N + col0 + (tx << 2) + 64] = o1;
    }
}

// ---------------------------------------------------------------------------
__device__ __forceinline__ float tanh_fast(float x) {
    float ax = fabsf(x);
    float e  = __expf(2.0f * ax);
    float t  = 1.0f - 2.0f / (e + 1.0f);
    return copysignf(t, x);
}

// ---------------------------------------------------------------------------
// Kernel 2: 4-row interleaved scan. Per step:
//   phase 1: 4 rows x 128 FMA partials (k-chunk kc) -> part_s      [VALU-dense]
//   A: barrier
//   phase 2: every thread combines+publishes row kc, col cg*128+c  [1 pkt/thr]
//   phase 3: poll 4 rows at column tid (latencies overlap)
//   phase 4: LN x4 (wave shuffle + LDS), tanh, store, h_s update
//   B,C: barriers
// NO inline asm; __launch_bounds__(512,2) grants a 256-VGPR budget so the
// w[128] slice cannot spill (round-1 lesson: VGPR_Count must be > 128).
// ---------------------------------------------------------------------------
__global__ __launch_bounds__(NTH, 2)
void rnn_scan5(const float* __restrict__ Wh, const float* __restrict__ h0,
               const float* __restrict__ gamma, const float* __restrict__ beta,
               float* __restrict__ out,
               unsigned long long* __restrict__ zbuf) {
    const int rg  = blockIdx.x & (RGN - 1);    // 0..15 rowgroup
    const int cg  = blockIdx.x >> 4;           // 0..3  column-group
    const int tid = threadIdx.x;               // 0..511
    const int c   = tid & (CGW - 1);           // 0..127
    const int kc  = tid >> 7;                  // 0..3 (k-chunk AND publish-row)

    __shared__ float h_s[RPW][H_DIM];          // 8 KB
    __shared__ float part_s[RPW][NCG][CGW];    // 8 KB
    __shared__ float wred_s[RPW][16];          // 256 B

    // Wh register slice, shared by all 4 rows: w[j] = Wh[kc*128+j][cg*128+c]
    float w[128];
    #pragma unroll
    for (int j = 0; j < 128; ++j)
        w[j] = Wh[(size_t)(kc * 128 + j) * H_DIM + cg * CGW + c];

    #pragma unroll
    for (int i = 0; i < RPW; ++i)
        h_s[i][tid] = h0[(rg + RGN * i) * H_DIM + tid];

    const float g_own = gamma[tid];
    const float b_own = beta[tid];

    // publish row for this thread (requires RPW == NCG): r_pub = rg + 16*kc
    const int r_pub = rg + RGN * kc;
    const float* xp_base = out + (size_t)r_pub * T_STEPS * H_DIM + cg * CGW + c;
    unsigned long long* zpub = zbuf + (size_t)r_pub * 2 * H_DIM + cg * CGW + c;

    // xp prefetch one step ahead (consumed by the publish-combine for r_pub)
    float xp_next = __builtin_nontemporal_load(xp_base);
    __syncthreads();

    for (int t = 0; t < T_STEPS; ++t) {
        const size_t par = (size_t)(t & 1) * H_DIM;
        const unsigned int tag = (unsigned int)(t + 1);
        const float xp = xp_next;

        // ---- phase 1: partials for 4 rows (w reused from registers) ----
        #pragma unroll
        for (int i = 0; i < RPW; ++i) {
            const float4* h4 = (const float4*)&h_s[i][kc * 128];
            float a0 = 0.0f, a1 = 0.0f, a2 = 0.0f, a3 = 0.0f;
            #pragma unroll
            for (int j4 = 0; j4 < 32; ++j4) {
                float4 hv = h4[j4];
                a0 = fmaf(w[4 * j4 + 0], hv.x, a0);
                a1 = fmaf(w[4 * j4 + 1], hv.y, a1);
                a2 = fmaf(w[4 * j4 + 2], hv.z, a2);
                a3 = fmaf(w[4 * j4 + 3], hv.w, a3);
            }
            part_s[i][kc][c] = (a0 + a1) + (a2 + a3);
        }
        __syncthreads();                                   // barrier A

        // ---- phase 2: combine + publish row kc (all 512 threads) ----
        {
            float zp = xp + part_s[kc][0][c] + part_s[kc][1][c]
                          + part_s[kc][2][c] + part_s[kc][3][c];
            unsigned long long pkt = ((unsigned long long)tag << 32)
                                   | (unsigned long long)__float_as_uint(zp);
            __hip_atomic_store(&zpub[par], pkt,
                               __ATOMIC_RELAXED, __HIP_MEMORY_SCOPE_AGENT);
        }

        // prefetch next xp while the publish drains
        if (t + 1 < T_STEPS)
            xp_next = __builtin_nontemporal_load(
                xp_base + (size_t)(t + 1) * H_DIM);

        // ---- phase 3: poll all 4 rows at column tid (overlapped) ----
        float z[RPW];
        {
            bool got0 = false, got1 = false, got2 = false, got3 = false;
            do {
                if (!got0) {
                    unsigned long long v = __hip_atomic_load(
                        &zbuf[(size_t)(rg + 0 * RGN) * 2 * H_DIM + par + tid],
                        __ATOMIC_RELAXED, __HIP_MEMORY_SCOPE_AGENT);
                    if ((unsigned)(v >> 32) == tag) { z[0] = __uint_as_float((unsigned)v); got0 = true; }
                }
                if (!got1) {
                    unsigned long long v = __hip_atomic_load(
                        &zbuf[(size_t)(rg + 1 * RGN) * 2 * H_DIM + par + tid],
                        __ATOMIC_RELAXED, __HIP_MEMORY_SCOPE_AGENT);
                    if ((unsigned)(v >> 32) == tag) { z[1] = __uint_as_float((unsigned)v); got1 = true; }
                }
                if (!got2) {
                    unsigned long long v = __hip_atomic_load(
                        &zbuf[(size_t)(rg + 2 * RGN) * 2 * H_DIM + par + tid],
                        __ATOMIC_RELAXED, __HIP_MEMORY_SCOPE_AGENT);
                    if ((unsigned)(v >> 32) == tag) { z[2] = __uint_as_float((unsigned)v); got2 = true; }
                }
                if (!got3) {
                    unsigned long long v = __hip_atomic_load(
                        &zbuf[(size_t)(rg + 3 * RGN) * 2 * H_DIM + par + tid],
                        __ATOMIC_RELAXED, __HIP_MEMORY_SCOPE_AGENT);
                    if ((unsigned)(v >> 32) == tag) { z[3] = __uint_as_float((unsigned)v); got3 = true; }
                }
            } while (!(got0 && got1 && got2 && got3));
        }

        // ---- phase 4: LN x 4 rows (fold orders identical to scan3) ----
        float s[RPW], q[RPW];
        #pragma unroll
        for (int i = 0; i < RPW; ++i) { s[i] = z[i]; q[i] = z[i] * z[i]; }
        #pragma unroll
        for (int o = 32; o > 0; o >>= 1) {
            #pragma unroll
            for (int i = 0; i < RPW; ++i) {
                s[i] += __shfl_down(s[i], o, 64);
                q[i] += __shfl_down(q[i], o, 64);
            }
        }
        const int wid = tid >> 6;
        if ((tid & 63) == 0) {
            #pragma unroll
            for (int i = 0; i < RPW; ++i) {
                wred_s[i][wid]     = s[i];
                wred_s[i][8 + wid] = q[i];
            }
        }
        __syncthreads();                                   // barrier B

        #pragma unroll
        for (int i = 0; i < RPW; ++i) {
            float S = 0.0f, Q = 0.0f;
            #pragma unroll
            for (int k = 0; k < 8; ++k) { S += wred_s[i][k]; Q += wred_s[i][8 + k]; }
            float mean = S * (1.0f / H_DIM);
            float var  = Q * (1.0f / H_DIM) - mean * mean;
            float rstd = rsqrtf(var + 1e-3f);              // keras LN eps
            float hn = tanh_fast((z[i] - mean) * rstd * g_own + b_own);
            if (kc == cg)
                __builtin_nontemporal_store(hn,
                    &out[((size_t)(rg + RGN * i) * T_STEPS + t) * H_DIM + tid]);
            h_s[i][tid] = hn;   // reads of h_s ended before barrier A
        }
        __syncthreads();                                   // barrier C
    }
}

// ---------------------------------------------------------------------------
extern "C" void kernel_launch(void* const* d_in, const int* in_sizes, int n_in,
                              void* d_out, int out_size, void* d_ws, size_t ws_size,
                              hipStream_t stream) {
    const float* inputs = (const float*)d_in[0];  // [B,T,D]
    const float* h0     = (const float*)d_in[1];  // [B,H]
    const float* Wx     = (const float*)d_in[2];  // [D,H]
    const float* Wh     = (const float*)d_in[3];  // [H,H]
    const float* bias   = (const float*)d_in[4];  // [H]
    const float* gamma  = (const float*)d_in[5];  // [H]
    const float* beta   = (const float*)d_in[6];  // [H]
    float* out = (float*)d_out;                   // [B,T,H]

    unsigned long long* zbuf = (unsigned long long*)d_ws;  // 512 KB

    const int M = B_SZ * T_STEPS;                 // 32768
    dim3 g1(H_DIM / BN, M / BM);                  // (4, 512)
    xproj_gemm<<<g1, 256, 0, stream>>>(inputs, Wx, bias, out, M, H_DIM, D_DIM);

    rnn_scan5<<<RGN * NCG, NTH, 0, stream>>>(Wh, h0, gamma, beta, out, zbuf);
}

// Round 3
// 1265.446 us; speedup vs baseline: 3.0833x; 2.5056x over previous
//
#include <hip/hip_runtime.h>
#include <cstdint>
#include <cstddef>

// Problem constants: B=64, T=512, D=256, H=512
#define T_STEPS 512
#define D_DIM 256
#define H_DIM 512
#define B_SZ 64

// rnn_scan6: 8 column-groups of 64 cols per row -> grid = 64 rows x 8 cg =
// 512 WGs of 512 threads = 2 WGs per CU (16 waves @ <=128 VGPR). While one
// WG spins on its exchange round-trip, the co-resident WG (a DIFFERENT row,
// bid and bid+256 differ in row) computes -- cross-WG latency hiding via the
// CU wave scheduler, which round-2 showed cannot be emulated inside one WG.
// Exchange protocol byte-identical to the harness-verified scan3: combined
// (tag|z) u64 packet, relaxed AGENT scope, 2-parity buffer, 1 poll/thread.
// Same-row octet = 8 consecutive blocks -> co-resident under in-order
// dispatch even at 1 WG/CU (no deadlock).
#define NCG 8
#define CGW (H_DIM / NCG)   // 64
#define NTH 512

// d_ws layout: zbuf u64[64 rows][2 parity][512 cols] = 512 KB.
// 0xAAAAAAAA poison never equals a tag in 1..512; ws re-poisoned per iter.

// ---------------------------------------------------------------------------
// Kernel 1: xproj = inputs @ Wx + bias  ->  d_out  [B*T, H]   (unchanged)
// ---------------------------------------------------------------------------
#define BM 64
#define BN 128
#define BK 32

__global__ __launch_bounds__(256)
void xproj_gemm(const float* __restrict__ A, const float* __restrict__ Bm,
                const float* __restrict__ bias, float* __restrict__ C,
                int M, int N, int K) {
    __shared__ float As[BK][BM];
    __shared__ float Bs[BK][BN];

    const int tid = threadIdx.x;
    const int tx = tid & 15;
    const int ty = tid >> 4;
    const int row0 = blockIdx.y * BM;
    const int col0 = blockIdx.x * BN;

    float acc[4][8];
    #pragma unroll
    for (int i = 0; i < 4; ++i)
        #pragma unroll
        for (int j = 0; j < 8; ++j) acc[i][j] = 0.0f;

    for (int kt = 0; kt < K; kt += BK) {
        #pragma unroll
        for (int i = 0; i < 2; ++i) {
            int q  = tid + i * 256;
            int m  = q >> 3;
            int k4 = (q & 7) << 2;
            float4 v = *(const float4*)&A[(size_t)(row0 + m) * K + kt + k4];
            As[k4 + 0][m] = v.x; As[k4 + 1][m] = v.y;
            As[k4 + 2][m] = v.z; As[k4 + 3][m] = v.w;
        }
        #pragma unroll
        for (int i = 0; i < 4; ++i) {
            int q  = tid + i * 256;
            int kk = q >> 5;
            int n4 = (q & 31) << 2;
            *(float4*)&Bs[kk][n4] = *(const float4*)&Bm[(size_t)(kt + kk) * N + col0 + n4];
        }
        __syncthreads();
        #pragma unroll
        for (int k = 0; k < BK; ++k) {
            float4 a  = *(const float4*)&As[k][ty << 2];
            float4 b0 = *(const float4*)&Bs[k][tx << 2];
            float4 b1 = *(const float4*)&Bs[k][(tx << 2) + 64];
            float av[4] = {a.x, a.y, a.z, a.w};
            float bv[8] = {b0.x, b0.y, b0.z, b0.w, b1.x, b1.y, b1.z, b1.w};
            #pragma unroll
            for (int i = 0; i < 4; ++i)
                #pragma unroll
                for (int j = 0; j < 8; ++j)
                    acc[i][j] = fmaf(av[i], bv[j], acc[i][j]);
        }
        __syncthreads();
    }

    float bv0[4], bv1[4];
    #pragma unroll
    for (int j = 0; j < 4; ++j) {
        bv0[j] = bias[col0 + (tx << 2) + j];
        bv1[j] = bias[col0 + (tx << 2) + 64 + j];
    }
    #pragma unroll
    for (int i = 0; i < 4; ++i) {
        int r = row0 + (ty << 2) + i;
        float4 o0 = make_float4(acc[i][0] + bv0[0], acc[i][1] + bv0[1],
                                acc[i][2] + bv0[2], acc[i][3] + bv0[3]);
        float4 o1 = make_float4(acc[i][4] + bv1[0], acc[i][5] + bv1[1],
                                acc[i][6] + bv1[2], acc[i][7] + bv1[3]);
        *(float4*)&C[(size_t)r * N + col0 + (tx << 2)]      = o0;
        *(float4*)&C[(size_t)r * N + col0 + (tx << 2) + 64] = o1;
    }
}

// ---------------------------------------------------------------------------
__device__ __forceinline__ float tanh_fast(float x) {
    float ax = fabsf(x);
    float e  = __expf(2.0f * ax);
    float t  = 1.0f - 2.0f / (e + 1.0f);
    return copysignf(t, x);
}

// ---------------------------------------------------------------------------
// Kernel 2: 8-way column-split scan, 2 WGs/CU.
// Thread layout: c = tid&63 (column within group), kc = tid>>6 (k-chunk,
// == wave id, so h_s reads are wave-uniform broadcasts).
// Per step: 64-FMA partial -> barrier A -> wave 0 combines+publishes the
// WG's 64 columns -> all threads poll global column tid -> LN (identical
// fold to scan3) -> tanh -> own-slice store -> h_s update -> barrier C.
// __launch_bounds__(512, 4): 128-VGPR cap => 16 waves/CU => 2 WGs/CU.
// ---------------------------------------------------------------------------
__global__ __launch_bounds__(NTH, 4)
void rnn_scan6(const float* __restrict__ Wh, const float* __restrict__ h0,
               const float* __restrict__ gamma, const float* __restrict__ beta,
               float* __restrict__ out,
               unsigned long long* __restrict__ zbuf) {
    const int cg  = blockIdx.x & (NCG - 1);    // 0..7 column-group
    const int r   = blockIdx.x >> 3;           // 0..63 row
    const int tid = threadIdx.x;               // 0..511
    const int c   = tid & (CGW - 1);           // 0..63
    const int kc  = tid >> 6;                  // 0..7 == wave id

    __shared__ float h_s[H_DIM];               // 2 KB
    __shared__ float part_s[NCG][CGW];         // 2 KB
    __shared__ float wred_s[16];

    // Wh register slice: w[j] = Wh[kc*64 + j][cg*64 + c]   (64 VGPRs)
    float w[64];
    #pragma unroll
    for (int j = 0; j < 64; ++j)
        w[j] = Wh[(size_t)(kc * CGW + j) * H_DIM + cg * CGW + c];

    h_s[tid] = h0[r * H_DIM + tid];
    const float g_own = gamma[tid];
    const float b_own = beta[tid];
    float* outrow = out + (size_t)r * T_STEPS * H_DIM;
    unsigned long long* zrow0 = zbuf + (size_t)(r * 2) * H_DIM;

    // xp prefetch one step ahead (combiner threads tid<64 only)
    float xp_next = 0.0f;
    if (tid < CGW)
        xp_next = __builtin_nontemporal_load(&outrow[cg * CGW + tid]);
    __syncthreads();

    for (int t = 0; t < T_STEPS; ++t) {
        unsigned long long* zrow = zrow0 + (size_t)(t & 1) * H_DIM;
        const unsigned int tag = (unsigned int)(t + 1);
        const float xp = xp_next;

        // partial z for own (column, k-chunk): 4 independent FMA chains
        const float4* h4 = (const float4*)&h_s[kc * CGW];
        float a0 = 0.0f, a1 = 0.0f, a2 = 0.0f, a3 = 0.0f;
        #pragma unroll
        for (int j4 = 0; j4 < 16; ++j4) {
            float4 hv = h4[j4];
            a0 = fmaf(w[4 * j4 + 0], hv.x, a0);
            a1 = fmaf(w[4 * j4 + 1], hv.y, a1);
            a2 = fmaf(w[4 * j4 + 2], hv.z, a2);
            a3 = fmaf(w[4 * j4 + 3], hv.w, a3);
        }
        part_s[kc][c] = (a0 + a1) + (a2 + a3);
        __syncthreads();                                   // barrier A

        // wave 0: combine 8 partials + xp, publish the WG's 64 columns
        if (tid < CGW) {
            float z = xp;
            #pragma unroll
            for (int k = 0; k < NCG; ++k) z += part_s[k][tid];
            unsigned long long pkt = ((unsigned long long)tag << 32)
                                   | (unsigned long long)__float_as_uint(z);
            __hip_atomic_store(&zrow[cg * CGW + tid], pkt,
                               __ATOMIC_RELAXED, __HIP_MEMORY_SCOPE_AGENT);
        }

        // prefetch next xp while the publish drains
        if (tid < CGW && t + 1 < T_STEPS)
            xp_next = __builtin_nontemporal_load(
                &outrow[(size_t)(t + 1) * H_DIM + cg * CGW + tid]);

        // every thread polls the packet for global column `tid`
        unsigned long long pkt;
        do {
            pkt = __hip_atomic_load(&zrow[tid], __ATOMIC_RELAXED,
                                    __HIP_MEMORY_SCOPE_AGENT);
        } while ((unsigned int)(pkt >> 32) != tag);
        float z = __uint_as_float((unsigned int)pkt);

        // LN stats over 512: wave shuffle + LDS, fold identical to scan3
        float s = z, q = z * z;
        #pragma unroll
        for (int o = 32; o > 0; o >>= 1) {
            s += __shfl_down(s, o, 64);
            q += __shfl_down(q, o, 64);
        }
        if ((tid & 63) == 0) { wred_s[kc] = s; wred_s[8 + kc] = q; }
        __syncthreads();                                   // barrier B
        float S = 0.0f, Q = 0.0f;
        #pragma unroll
        for (int i = 0; i < 8; ++i) { S += wred_s[i]; Q += wred_s[8 + i]; }
        float mean = S * (1.0f / H_DIM);
        float var  = Q * (1.0f / H_DIM) - mean * mean;
        float rstd = rsqrtf(var + 1e-3f);                  // keras LN eps

        float hn = tanh_fast((z - mean) * rstd * g_own + b_own);
        if (kc == cg)                                      // own 64-col slice
            __builtin_nontemporal_store(hn, &outrow[(size_t)t * H_DIM + tid]);
        h_s[tid] = hn;            // reads of h_s ended before barrier A
        __syncthreads();                                   // barrier C
    }
}

// ---------------------------------------------------------------------------
extern "C" void kernel_launch(void* const* d_in, const int* in_sizes, int n_in,
                              void* d_out, int out_size, void* d_ws, size_t ws_size,
                              hipStream_t stream) {
    const float* inputs = (const float*)d_in[0];  // [B,T,D]
    const float* h0     = (const float*)d_in[1];  // [B,H]
    const float* Wx     = (const float*)d_in[2];  // [D,H]
    const float* Wh     = (const float*)d_in[3];  // [H,H]
    const float* bias   = (const float*)d_in[4];  // [H]
    const float* gamma  = (const float*)d_in[5];  // [H]
    const float* beta   = (const float*)d_in[6];  // [H]
    float* out = (float*)d_out;                   // [B,T,H]

    unsigned long long* zbuf = (unsigned long long*)d_ws;  // 512 KB

    const int M = B_SZ * T_STEPS;                 // 32768
    dim3 g1(H_DIM / BN, M / BM);                  // (4, 512)
    xproj_gemm<<<g1, 256, 0, stream>>>(inputs, Wx, bias, out, M, H_DIM, D_DIM);

    // bid = cg + 8*row: same-row octet = 8 consecutive blocks (co-resident,
    // deadlock-free); bid and bid+256 differ in row -> each CU's 2 WGs are
    // different rows -> exchange latency of one hides under the other.
    rnn_scan6<<<B_SZ * NCG, NTH, 0, stream>>>(Wh, h0, gamma, beta, out, zbuf);
}